// Round 1
// baseline (245.543 us; speedup 1.0000x reference)
//
#include <hip/hip_runtime.h>

// out[b, n] = sum_k x[b,k] * w[n,k]
// B=8, S=1, K=4096, N=11008, fp32.
// HBM-bound on the 180 MB weight stream. Each wave owns 2 output rows and
// computes all 8 batch dot-products per weight read (8x arithmetic intensity
// per weight byte). x is staged into LDS in 32 KB chunks.

#define BATCH 8
#define KDIM 4096
#define NDIM 11008
#define KC 1024               // K-chunk staged into LDS (8*1024*4 = 32 KB)
#define BLOCK 256             // 4 waves
#define ROWS_PER_WAVE 2
#define ROWS_PER_BLOCK 8      // 4 waves * 2 rows

__global__ __launch_bounds__(BLOCK)
void ActivationSparseLinear_4982162063725_kernel(const float* __restrict__ x,
                                                 const float* __restrict__ w,
                                                 float* __restrict__ out) {
    __shared__ float4 xs[BATCH * (KC / 4)];   // 8 batches x 256 float4 = 32 KB

    const int tid  = threadIdx.x;
    const int lane = tid & 63;
    const int wave = tid >> 6;
    const int n0   = blockIdx.x * ROWS_PER_BLOCK + wave * ROWS_PER_WAVE;

    const float4* xg4 = (const float4*)x;     // [BATCH][KDIM/4]
    const float4* wg4 = (const float4*)w;     // [NDIM][KDIM/4]

    float acc[ROWS_PER_WAVE][BATCH];
#pragma unroll
    for (int r = 0; r < ROWS_PER_WAVE; ++r)
#pragma unroll
        for (int b = 0; b < BATCH; ++b) acc[r][b] = 0.0f;

    const float4* wrow0 = wg4 + (size_t)(n0 + 0) * (KDIM / 4);
    const float4* wrow1 = wg4 + (size_t)(n0 + 1) * (KDIM / 4);

    for (int c = 0; c < KDIM / KC; ++c) {
        // Stage x[:, c*KC .. c*KC+KC) into LDS. 2048 float4 total, 8 per thread,
        // each j is one fully-coalesced 256-lane float4 load.
#pragma unroll
        for (int j = 0; j < BATCH; ++j) {
            xs[j * (KC / 4) + tid] = xg4[j * (KDIM / 4) + c * (KC / 4) + tid];
        }
        __syncthreads();

#pragma unroll
        for (int i = 0; i < KC / 256; ++i) {
            float4 xv[BATCH];
#pragma unroll
            for (int b = 0; b < BATCH; ++b)
                xv[b] = xs[b * (KC / 4) + i * 64 + lane];   // ds_read_b128, conflict-free

            const int kk = c * (KC / 4) + i * 64 + lane;    // float4 index into row
            const float4 w0 = wrow0[kk];                    // coalesced 1 KB/wave
            const float4 w1 = wrow1[kk];

#pragma unroll
            for (int b = 0; b < BATCH; ++b) {
                acc[0][b] += w0.x * xv[b].x + w0.y * xv[b].y + w0.z * xv[b].z + w0.w * xv[b].w;
                acc[1][b] += w1.x * xv[b].x + w1.y * xv[b].y + w1.z * xv[b].z + w1.w * xv[b].w;
            }
        }
        __syncthreads();
    }

    // Butterfly-reduce each accumulator across the 64-lane wave.
#pragma unroll
    for (int r = 0; r < ROWS_PER_WAVE; ++r)
#pragma unroll
        for (int b = 0; b < BATCH; ++b) {
            float v = acc[r][b];
#pragma unroll
            for (int off = 32; off > 0; off >>= 1)
                v += __shfl_xor(v, off, 64);
            acc[r][b] = v;
        }

    if (lane == 0) {
#pragma unroll
        for (int r = 0; r < ROWS_PER_WAVE; ++r)
#pragma unroll
            for (int b = 0; b < BATCH; ++b)
                out[(size_t)b * NDIM + n0 + r] = acc[r][b];
    }
}

extern "C" void kernel_launch(void* const* d_in, const int* in_sizes, int n_in,
                              void* d_out, int out_size, void* d_ws, size_t ws_size,
                              hipStream_t stream) {
    const float* x = (const float*)d_in[0];   // (8, 1, 4096) fp32
    const float* w = (const float*)d_in[1];   // (11008, 4096) fp32
    float* out = (float*)d_out;               // (8, 1, 11008) fp32

    dim3 grid(NDIM / ROWS_PER_BLOCK);         // 1376 blocks, exact fit
    ActivationSparseLinear_4982162063725_kernel<<<grid, BLOCK, 0, stream>>>(x, w, out);
}